// Round 6
// baseline (127.150 us; speedup 1.0000x reference)
//
#include <hip/hip_runtime.h>
#include <hip/hip_bf16.h>

typedef __attribute__((ext_vector_type(8))) __bf16 bf16x8;
typedef __attribute__((ext_vector_type(4))) float f32x4;
typedef __attribute__((ext_vector_type(4))) int int4v;

#define NB 8
#define NN 2048
#define ND 256
#define L2E 1.44269504f

// ---------------------------------------------------------------------------
// K2: per block recompute wl/wr = W^T a halves (L2-hot W), then row dots.
// Outputs pre-scaled score tables:
//   elc[bn]    = (-0.8*el - 16) * log2e
//   er2[bn*2]  = (er - 16) * log2e,  er2[bn*2+1] = 0.2*er * log2e
// (score exponent in k3 = max(er2.x, er2.y + elc) -> exp2)
// ---------------------------------------------------------------------------
__global__ __launch_bounds__(256) void k2_elr(
    const float* __restrict__ x, const float* __restrict__ W,
    const float* __restrict__ a, float* __restrict__ elc,
    float* __restrict__ er2) {
  __shared__ float wls[ND], wrs[ND];
  int t = threadIdx.x;
  {
    float swl = 0.f, swr = 0.f;
    for (int o = 0; o < ND; ++o) {
      float wv = W[(long)o * ND + t];
      swl = fmaf(a[o], wv, swl);
      swr = fmaf(a[ND + o], wv, swr);
    }
    wls[t] = swl;
    wrs[t] = swr;
  }
  __syncthreads();
  int r = t >> 2, q = t & 3;
  long row = (long)blockIdx.x * 64 + r;
  const f32x4* xr = (const f32x4*)(x + row * ND);
  float sl = 0.f, sr = 0.f;
#pragma unroll
  for (int ii = 0; ii < 16; ++ii) {
    int idx = q + (ii << 2);
    f32x4 xv = xr[idx];
    f32x4 lv = *(const f32x4*)(wls + idx * 4);
    f32x4 rv = *(const f32x4*)(wrs + idx * 4);
    sl += xv[0] * lv[0] + xv[1] * lv[1] + xv[2] * lv[2] + xv[3] * lv[3];
    sr += xv[0] * rv[0] + xv[1] * rv[1] + xv[2] * rv[2] + xv[3] * rv[3];
  }
  sl += __shfl_xor(sl, 1);
  sl += __shfl_xor(sl, 2);
  sr += __shfl_xor(sr, 1);
  sr += __shfl_xor(sr, 2);
  if (q == 0) {
    elc[row] = (-0.8f * sl - 16.0f) * L2E;
    float2 v;
    v.x = (sr - 16.0f) * L2E;
    v.y = 0.2f * sr * L2E;
    *(float2*)(er2 + row * 2) = v;
  }
}

// ---------------------------------------------------------------------------
// K1: h = x @ W^T via bf16 MFMA; write hT[b][d][n] bf16 (transposed via LDS).
// ---------------------------------------------------------------------------
__global__ __launch_bounds__(256) void k1_h(
    const float* __restrict__ x, const float* __restrict__ W,
    __bf16* __restrict__ hT) {
  __shared__ __bf16 hlds[256 * 34];
  int tid = threadIdx.x;
  int wid = tid >> 6, lane = tid & 63;
  int msub = wid & 1, nh = wid >> 1;
  int lrow = lane & 15, kg = lane >> 4;
  int m0 = blockIdx.x * 32;
  int row = m0 + msub * 16 + lrow;

  f32x4 acc[8];
#pragma unroll
  for (int f = 0; f < 8; ++f) acc[f] = (f32x4){0.f, 0.f, 0.f, 0.f};

#pragma unroll
  for (int k0 = 0; k0 < ND; k0 += 32) {
    int kk = k0 + kg * 8;
    const f32x4* xa = (const f32x4*)(x + (long)row * ND + kk);
    f32x4 a0 = xa[0], a1 = xa[1];
    bf16x8 afrag;
    afrag[0] = (__bf16)a0[0]; afrag[1] = (__bf16)a0[1];
    afrag[2] = (__bf16)a0[2]; afrag[3] = (__bf16)a0[3];
    afrag[4] = (__bf16)a1[0]; afrag[5] = (__bf16)a1[1];
    afrag[6] = (__bf16)a1[2]; afrag[7] = (__bf16)a1[3];
#pragma unroll
    for (int f = 0; f < 8; ++f) {
      int o = nh * 128 + f * 16 + lrow;
      const f32x4* wb = (const f32x4*)(W + (long)o * ND + kk);
      f32x4 b0 = wb[0], b1 = wb[1];
      bf16x8 bfrag;
      bfrag[0] = (__bf16)b0[0]; bfrag[1] = (__bf16)b0[1];
      bfrag[2] = (__bf16)b0[2]; bfrag[3] = (__bf16)b0[3];
      bfrag[4] = (__bf16)b1[0]; bfrag[5] = (__bf16)b1[1];
      bfrag[6] = (__bf16)b1[2]; bfrag[7] = (__bf16)b1[3];
      acc[f] = __builtin_amdgcn_mfma_f32_16x16x32_bf16(afrag, bfrag, acc[f], 0, 0, 0);
    }
  }

#pragma unroll
  for (int f = 0; f < 8; ++f) {
    int d = nh * 128 + f * 16 + lrow;
#pragma unroll
    for (int r = 0; r < 4; ++r) {
      int nloc = msub * 16 + kg * 4 + r;
      hlds[d * 34 + nloc] = (__bf16)acc[f][r];
    }
  }
  __syncthreads();
  {
    int b = m0 >> 11;
    int n0 = m0 & (NN - 1);
    const int* src = (const int*)(hlds + tid * 34);
    int tmp[16];
#pragma unroll
    for (int j = 0; j < 16; ++j) tmp[j] = src[j];
    __bf16* dst = hT + ((long)b * ND + tid) * NN + n0;
#pragma unroll
    for (int j = 0; j < 4; ++j)
      *(int4v*)(dst + j * 8) = *(int4v*)(tmp + j * 4);
  }
}

// ---------------------------------------------------------------------------
// K3: fused adj-stream + mask + softmax + PV.
// 32-j chunks; hT chunk (16 KB) triple-buffered via global_load_lds (4 insts/
// thread, linear dest, source pre-swizzled; ds_read slot = kg^((lrow>>1)&3)
// -> 2-way (free) bank access). adj (2x int4) + er2 (4x f32x4) prefetched into
// 3 static register sets, 2 chunks ahead. Chunk loop unrolled x3 so every
// buffer/set index and address is compile-time. vmcnt(10) counted (one chunk
// in flight), raw s_barrier, one barrier per chunk.
// ---------------------------------------------------------------------------
__global__ __launch_bounds__(256, 2) void k3_main(
    const int* __restrict__ adj, const __bf16* __restrict__ hT,
    const float* __restrict__ elc, const float* __restrict__ er2,
    float* __restrict__ out) {
  __shared__ __bf16 hbuf[3][256 * 32];  // 3 x 16 KB

  int blk = blockIdx.x;
  int b = blk & 7;    // batch -> XCD pin
  int it = blk >> 3;  // i-tile 0..63
  int tid = threadIdx.x;
  int wid = tid >> 6, lane = tid & 63;
  int isub = wid & 1, dh = wid >> 1;
  int lrow = lane & 15, kg = lane >> 4;
  int irow = it * 32 + isub * 16 + lrow;

  const __bf16* hTb = hT + (long)b * ND * NN;
  const int* adjrow = adj + ((long)b * NN + irow) * NN;
  const float* er2b = er2 + (long)b * NN * 2;
  float c1s = elc[b * NN + irow];
  int kg8 = kg * 8;

  // stage addressing: dest idx16 = rr*256+tid -> (d = idx>>2, spp = idx&3),
  // logical j-slot = spp ^ ((d>>1)&3); (d>>1)&3 is rr-invariant for d0=tid>>2.
  int d0 = tid >> 2;
  int spp = tid & 3;
  int jlog = (spp ^ ((d0 >> 1) & 3)) * 8;
  const __bf16* sbase = hTb + (long)d0 * NN + jlog;

  // ds_read: byte = d*64 + sp*16, sp = kg ^ ((lrow>>1)&3), d = dh*128+f*16+lrow
  int sp_r = kg ^ ((lrow >> 1) & 3);
  int hoff = (dh * 128 + lrow) * 64 + sp_r * 16;  // + f*1024
  int d_base = dh * 128 + lrow;

  f32x4 acc[8];
#pragma unroll
  for (int f = 0; f < 8; ++f) acc[f] = (f32x4){0.f, 0.f, 0.f, 0.f};
  float den = 0.f;

  int4v aj0_0, aj1_0, aj0_1, aj1_1, aj0_2, aj1_2;
  f32x4 e0_0, e1_0, e2_0, e3_0;
  f32x4 e0_1, e1_1, e2_1, e3_1;
  f32x4 e0_2, e1_2, e2_2, e3_2;

#define STAGEH(BI, TCV)                                                       \
  {                                                                           \
    const __bf16* s0 = sbase + (TCV)*32;                                      \
    _Pragma("unroll") for (int rr = 0; rr < 4; ++rr) {                        \
      __builtin_amdgcn_global_load_lds(                                       \
          (const __attribute__((address_space(1))) void*)(s0 + (long)rr * 64 * NN), \
          (__attribute__((address_space(3))) void*)(&hbuf[BI][0] +            \
                                                    (rr * 256 + tid) * 8),    \
          16, 0, 0);                                                          \
    }                                                                         \
  }

#define LOADSET(S, TCV)                                                       \
  {                                                                           \
    const int* ap = adjrow + (TCV)*32 + kg8;                                  \
    aj0_##S = *(const int4v*)(ap);                                            \
    aj1_##S = *(const int4v*)(ap + 4);                                        \
    const float* ep = er2b + ((TCV)*32 + kg8) * 2;                            \
    e0_##S = *(const f32x4*)(ep);                                             \
    e1_##S = *(const f32x4*)(ep + 4);                                         \
    e2_##S = *(const f32x4*)(ep + 8);                                         \
    e3_##S = *(const f32x4*)(ep + 12);                                        \
  }

#define COMPUTE(BI, S)                                                        \
  {                                                                           \
    bf16x8 pfrag;                                                             \
    float ps = 0.f;                                                           \
    _Pragma("unroll") for (int e = 0; e < 8; ++e) {                           \
      f32x4 ev = (e < 2) ? e0_##S : (e < 4) ? e1_##S : (e < 6) ? e2_##S : e3_##S; \
      float x16 = ev[(e & 1) * 2];                                            \
      float x02 = ev[(e & 1) * 2 + 1];                                        \
      int aj = (e < 4) ? aj0_##S[e] : aj1_##S[e & 3];                         \
      float m = fmaxf(x16, x02 + c1s);                                        \
      float p = __builtin_amdgcn_exp2f(m);                                    \
      p = aj ? p : 0.0f;                                                      \
      ps += p;                                                                \
      pfrag[e] = (__bf16)p;                                                   \
    }                                                                         \
    den += ps;                                                                \
    const char* hb = (const char*)&hbuf[BI][0];                               \
    __builtin_amdgcn_s_setprio(1);                                            \
    _Pragma("unroll") for (int f = 0; f < 8; ++f) {                           \
      bf16x8 bfr = *(const bf16x8*)(hb + hoff + f * 1024);                    \
      acc[f] = __builtin_amdgcn_mfma_f32_16x16x32_bf16(pfrag, bfr, acc[f], 0, 0, 0); \
    }                                                                         \
    __builtin_amdgcn_s_setprio(0);                                            \
  }

#define WAITB(VMN)                                            \
  asm volatile("s_waitcnt vmcnt(" VMN ")" ::: "memory");      \
  __builtin_amdgcn_s_barrier();

  // prologue: chunk0's 10 insts oldest, then chunk1's 10
  LOADSET(0, 0);
  STAGEH(0, 0);
  LOADSET(1, 1);
  STAGEH(1, 1);

  for (int t3 = 0; t3 < 20; ++t3) {
    int tc = t3 * 3;  // chunks tc, tc+1, tc+2 ; stages tc+2..tc+4 (<= 61)
    WAITB("10");
    STAGEH(2, tc + 2);
    LOADSET(2, tc + 2);
    COMPUTE(0, 0);
    WAITB("10");
    STAGEH(0, tc + 3);
    LOADSET(0, tc + 3);
    COMPUTE(1, 1);
    WAITB("10");
    STAGEH(1, tc + 4);
    LOADSET(1, tc + 4);
    COMPUTE(2, 2);
  }
  // epilogue: chunks 60..63 (60%3=0, 61->1, 62->2, 63->0)
  WAITB("10");
  STAGEH(2, 62);
  LOADSET(2, 62);
  COMPUTE(0, 0);
  WAITB("10");
  STAGEH(0, 63);
  LOADSET(0, 63);
  COMPUTE(1, 1);
  WAITB("10");
  COMPUTE(2, 2);
  WAITB("0");
  COMPUTE(0, 0);

#undef STAGEH
#undef LOADSET
#undef COMPUTE
#undef WAITB

  // den: sum across the 4 k-groups (lanes with same l&15)
  den += __shfl_xor(den, 16);
  den += __shfl_xor(den, 32);
  float rdiv[4];
#pragma unroll
  for (int r = 0; r < 4; ++r) rdiv[r] = 1.0f / __shfl(den, kg * 4 + r);

  float* outb = out + ((long)b * NN + it * 32 + isub * 16) * ND;
#pragma unroll
  for (int f = 0; f < 8; ++f) {
    int dcol = d_base + f * 16;
#pragma unroll
    for (int r = 0; r < 4; ++r)
      outb[(long)(kg * 4 + r) * ND + dcol] = acc[f][r] * rdiv[r];
  }
}

// ---------------------------------------------------------------------------
extern "C" void kernel_launch(void* const* d_in, const int* in_sizes, int n_in,
                              void* d_out, int out_size, void* d_ws,
                              size_t ws_size, hipStream_t stream) {
  const float* x = (const float*)d_in[0];
  const int* adj = (const int*)d_in[1];
  const float* W = (const float*)d_in[2];
  const float* a = (const float*)d_in[3];
  float* out = (float*)d_out;

  char* ws = (char*)d_ws;
  const size_t base = 8u * 1024u * 1024u;
  __bf16* hT = (__bf16*)ws;                   // 8 MB
  float* elc = (float*)(ws + base);           // 64 KB
  float* er2 = (float*)(ws + base + 65536u);  // 128 KB

  k1_h<<<dim3(512), dim3(256), 0, stream>>>(x, W, hT);
  k2_elr<<<dim3(256), dim3(256), 0, stream>>>(x, W, a, elc, er2);
  k3_main<<<dim3(512), dim3(256), 0, stream>>>(adj, hT, elc, er2, out);
}